// Round 3
// baseline (721.013 us; speedup 1.0000x reference)
//
#include <hip/hip_runtime.h>
#include <cstddef>

#define N_NODES 100000
#define N_EDGES 640000
#define D 128
#define LDSP 132      // LDS row pitch (floats): float4-aligned, stride-1 lane maps stay ~conflict-free
#define NGRP (N_NODES / 32)   // 3125 groups of 32 nodes

// ---------------------------------------------------------------------------
// 1) Count edges per 32-node destination group.
// ---------------------------------------------------------------------------
__global__ __launch_bounds__(256) void grp_count_kernel(
    const int* __restrict__ edge_dst, int* __restrict__ cnt)
{
    int e = blockIdx.x * 256 + threadIdx.x;
    if (e >= N_EDGES) return;
    atomicAdd(&cnt[edge_dst[e] >> 5], 1);
}

// ---------------------------------------------------------------------------
// 2) Exclusive scan of 3125 group counts (single block, 1024 threads, 4/thread).
// ---------------------------------------------------------------------------
__global__ __launch_bounds__(1024) void scan_kernel(
    const int* __restrict__ cnt, int* __restrict__ grp_start)
{
    __shared__ int sums[1024];
    const int t = threadIdx.x;
    int c[4];
    int s = 0;
#pragma unroll
    for (int j = 0; j < 4; ++j) {
        int idx = t * 4 + j;
        c[j] = (idx < NGRP) ? cnt[idx] : 0;
        s += c[j];
    }
    sums[t] = s;
    __syncthreads();
    for (int off = 1; off < 1024; off <<= 1) {
        int v = (t >= off) ? sums[t - off] : 0;
        __syncthreads();
        sums[t] += v;
        __syncthreads();
    }
    int excl = (t == 0) ? 0 : sums[t - 1];
#pragma unroll
    for (int j = 0; j < 4; ++j) {
        int idx = t * 4 + j;
        if (idx < NGRP) { grp_start[idx] = excl; excl += c[j]; }
    }
    if (t == 1023) grp_start[NGRP] = sums[1023];   // == N_EDGES
}

// ---------------------------------------------------------------------------
// 3) Fill group-bucketed edge list: entries[pos] = (src<<5) | (dst&31).
// ---------------------------------------------------------------------------
__global__ __launch_bounds__(256) void fill_kernel(
    const int* __restrict__ edge_src, const int* __restrict__ edge_dst,
    const int* __restrict__ grp_start, int* __restrict__ cursor,
    int* __restrict__ entries)
{
    int e = blockIdx.x * 256 + threadIdx.x;
    if (e >= N_EDGES) return;
    int dst = edge_dst[e];
    int g = dst >> 5;
    int pos = grp_start[g] + atomicAdd(&cursor[g], 1);
    entries[pos] = (edge_src[e] << 5) | (dst & 31);
}

// ---------------------------------------------------------------------------
// 4) Fused: edge-parallel gather-sum into LDS (ds_add_f32), scale to mean,
//    then out = mean @ weight + x @ root_weight + bias.
//    Block = 256 threads (4 waves), tile = 32 nodes x 128 cols.
// ---------------------------------------------------------------------------
__global__ __launch_bounds__(256) void sage_fused_gemm_kernel(
    const float* __restrict__ x,
    const float* __restrict__ weight,
    const float* __restrict__ root_weight,
    const float* __restrict__ bias,
    const int* __restrict__ grp_start,
    const int* __restrict__ entries,
    float* __restrict__ out)
{
    __shared__ float a_mean[32][LDSP];
    __shared__ float a_x[32][LDSP];
    __shared__ int s_deg[32];

    const int t = threadIdx.x;
    const int base = blockIdx.x * 32;

    if (t < 32) s_deg[t] = 0;
    // Zero mean tile + stage x tile (coalesced float4).
    for (int i = t; i < 32 * 32; i += 256) {
        int row = i >> 5;
        int c4 = i & 31;
        *reinterpret_cast<float4*>(&a_mean[row][c4 * 4]) = make_float4(0.f, 0.f, 0.f, 0.f);
        float4 vx = *reinterpret_cast<const float4*>(x + (size_t)(base + row) * D + c4 * 4);
        *reinterpret_cast<float4*>(&a_x[row][c4 * 4]) = vx;
    }
    __syncthreads();

    // Edge-parallel gather. Wave w takes edges eb+w, eb+w+4, ... (unroll x2).
    // Lane l owns dims l and l+64 -> ds_add at 2-way bank aliasing (free).
    const int wave = t >> 6;
    const int lane = t & 63;
    const int eb = grp_start[blockIdx.x];
    const int ee = grp_start[blockIdx.x + 1];

    int i = eb + wave;
    for (; i + 4 < ee; i += 8) {
        int ent0 = entries[i];
        int ent1 = entries[i + 4];
        int src0 = ent0 >> 5, loc0 = ent0 & 31;
        int src1 = ent1 >> 5, loc1 = ent1 & 31;
        float v0a = x[(size_t)src0 * D + lane];
        float v0b = x[(size_t)src0 * D + lane + 64];
        float v1a = x[(size_t)src1 * D + lane];
        float v1b = x[(size_t)src1 * D + lane + 64];
        atomicAdd(&a_mean[loc0][lane], v0a);
        atomicAdd(&a_mean[loc0][lane + 64], v0b);
        atomicAdd(&a_mean[loc1][lane], v1a);
        atomicAdd(&a_mean[loc1][lane + 64], v1b);
        if (lane == 0) {
            atomicAdd(&s_deg[loc0], 1);
            atomicAdd(&s_deg[loc1], 1);
        }
    }
    if (i < ee) {
        int ent = entries[i];
        int src = ent >> 5, loc = ent & 31;
        float va = x[(size_t)src * D + lane];
        float vb = x[(size_t)src * D + lane + 64];
        atomicAdd(&a_mean[loc][lane], va);
        atomicAdd(&a_mean[loc][lane + 64], vb);
        if (lane == 0) atomicAdd(&s_deg[loc], 1);
    }
    __syncthreads();

    // Scale sums -> mean. 8 threads per row, 16 floats each.
    {
        int row = t >> 3;
        int c0 = (t & 7) * 16;
        float inv = 1.0f / fmaxf((float)s_deg[row], 1.0f);
#pragma unroll
        for (int k = 0; k < 16; k += 4) {
            float4 v = *reinterpret_cast<float4*>(&a_mean[row][c0 + k]);
            v.x *= inv; v.y *= inv; v.z *= inv; v.w *= inv;
            *reinterpret_cast<float4*>(&a_mean[row][c0 + k]) = v;
        }
    }
    __syncthreads();

    const int tx = t & 31;
    const int ty = t >> 5;
    const int j0 = tx * 4;
    const int m0 = ty * 4;

    const float4 b4 = *reinterpret_cast<const float4*>(bias + j0);
    float acc[4][4];
#pragma unroll
    for (int m = 0; m < 4; ++m) {
        acc[m][0] = b4.x; acc[m][1] = b4.y; acc[m][2] = b4.z; acc[m][3] = b4.w;
    }

    // mean @ weight
    for (int k = 0; k < D; k += 4) {
        float4 w0 = *reinterpret_cast<const float4*>(weight + (size_t)(k + 0) * D + j0);
        float4 w1 = *reinterpret_cast<const float4*>(weight + (size_t)(k + 1) * D + j0);
        float4 w2 = *reinterpret_cast<const float4*>(weight + (size_t)(k + 2) * D + j0);
        float4 w3 = *reinterpret_cast<const float4*>(weight + (size_t)(k + 3) * D + j0);
#pragma unroll
        for (int m = 0; m < 4; ++m) {
            float4 a = *reinterpret_cast<const float4*>(&a_mean[m0 + m][k]);
            acc[m][0] += a.x * w0.x + a.y * w1.x + a.z * w2.x + a.w * w3.x;
            acc[m][1] += a.x * w0.y + a.y * w1.y + a.z * w2.y + a.w * w3.y;
            acc[m][2] += a.x * w0.z + a.y * w1.z + a.z * w2.z + a.w * w3.z;
            acc[m][3] += a.x * w0.w + a.y * w1.w + a.z * w2.w + a.w * w3.w;
        }
    }

    // x @ root_weight
    for (int k = 0; k < D; k += 4) {
        float4 w0 = *reinterpret_cast<const float4*>(root_weight + (size_t)(k + 0) * D + j0);
        float4 w1 = *reinterpret_cast<const float4*>(root_weight + (size_t)(k + 1) * D + j0);
        float4 w2 = *reinterpret_cast<const float4*>(root_weight + (size_t)(k + 2) * D + j0);
        float4 w3 = *reinterpret_cast<const float4*>(root_weight + (size_t)(k + 3) * D + j0);
#pragma unroll
        for (int m = 0; m < 4; ++m) {
            float4 a = *reinterpret_cast<const float4*>(&a_x[m0 + m][k]);
            acc[m][0] += a.x * w0.x + a.y * w1.x + a.z * w2.x + a.w * w3.x;
            acc[m][1] += a.x * w0.y + a.y * w1.y + a.z * w2.y + a.w * w3.y;
            acc[m][2] += a.x * w0.z + a.y * w1.z + a.z * w2.z + a.w * w3.z;
            acc[m][3] += a.x * w0.w + a.y * w1.w + a.z * w2.w + a.w * w3.w;
        }
    }

#pragma unroll
    for (int m = 0; m < 4; ++m) {
        *reinterpret_cast<float4*>(out + (size_t)(base + m0 + m) * D + j0) =
            make_float4(acc[m][0], acc[m][1], acc[m][2], acc[m][3]);
    }
}

extern "C" void kernel_launch(void* const* d_in, const int* in_sizes, int n_in,
                              void* d_out, int out_size, void* d_ws, size_t ws_size,
                              hipStream_t stream) {
    const float* x           = (const float*)d_in[0];
    const float* weight      = (const float*)d_in[1];
    const float* root_weight = (const float*)d_in[2];
    const float* bias        = (const float*)d_in[3];
    const int* edge_src      = (const int*)d_in[4];
    const int* edge_dst      = (const int*)d_in[5];
    float* out = (float*)d_out;

    // ws layout (ints): cnt[NGRP] | cursor[NGRP] | grp_start[NGRP+1] | entries[E]
    int* cnt       = (int*)d_ws;
    int* cursor    = cnt + NGRP;
    int* grp_start = cursor + NGRP;
    int* entries   = grp_start + (NGRP + 1);

    hipMemsetAsync(cnt, 0, 2 * (size_t)NGRP * sizeof(int), stream);

    const int eb = (N_EDGES + 255) / 256;   // 2500
    grp_count_kernel<<<eb, 256, 0, stream>>>(edge_dst, cnt);
    scan_kernel<<<1, 1024, 0, stream>>>(cnt, grp_start);
    fill_kernel<<<eb, 256, 0, stream>>>(edge_src, edge_dst, grp_start, cursor, entries);
    sage_fused_gemm_kernel<<<NGRP, 256, 0, stream>>>(
        x, weight, root_weight, bias, grp_start, entries, out);
}

// Round 4
// 155.549 us; speedup vs baseline: 4.6353x; 4.6353x over previous
//
#include <hip/hip_runtime.h>
#include <cstddef>

#define N_NODES 100000
#define N_EDGES 640000
#define D 128

#define SCAN_N (N_NODES + 1)                 // 100001
#define SCAN_B ((SCAN_N + 1023) / 1024)      // 98

typedef __attribute__((ext_vector_type(4))) float f32x4;
typedef __attribute__((ext_vector_type(8))) short bf16x8;

__device__ __forceinline__ unsigned short f2bf(float f) {
    union { float f; unsigned int u; } v; v.f = f;
    unsigned int u = v.u;
    unsigned int r = (u + 0x7FFFu + ((u >> 16) & 1u)) >> 16;   // RNE
    return (unsigned short)r;
}

// ---------------------------------------------------------------------------
// 1) In-degree count into A[] (becomes row_start after in-place scan).
// ---------------------------------------------------------------------------
__global__ __launch_bounds__(256) void deg_count_kernel(
    const int* __restrict__ edge_dst, int* __restrict__ A)
{
    int e = blockIdx.x * 256 + threadIdx.x;
    if (e < N_EDGES) atomicAdd(&A[edge_dst[e]], 1);
}

// ---------------------------------------------------------------------------
// 2a) Per-block partial sums of A[0..SCAN_N).
// ---------------------------------------------------------------------------
__global__ __launch_bounds__(1024) void scan_part_kernel(
    const int* __restrict__ A, int* __restrict__ partials)
{
    __shared__ int red[1024];
    int t = threadIdx.x;
    int gid = blockIdx.x * 1024 + t;
    red[t] = (gid < SCAN_N) ? A[gid] : 0;
    __syncthreads();
    for (int s = 512; s > 0; s >>= 1) {
        if (t < s) red[t] += red[t + s];
        __syncthreads();
    }
    if (t == 0) partials[blockIdx.x] = red[0];
}

// ---------------------------------------------------------------------------
// 2b) Exclusive scan of the 98 partials (single small block).
// ---------------------------------------------------------------------------
__global__ __launch_bounds__(128) void scan_offs_kernel(int* __restrict__ partials)
{
    __shared__ int sums[128];
    int t = threadIdx.x;
    int v = (t < SCAN_B) ? partials[t] : 0;
    sums[t] = v;
    __syncthreads();
    for (int off = 1; off < 128; off <<= 1) {
        int u = (t >= off) ? sums[t - off] : 0;
        __syncthreads();
        sums[t] += u;
        __syncthreads();
    }
    if (t < SCAN_B) partials[t] = sums[t] - v;   // exclusive
}

// ---------------------------------------------------------------------------
// 2c) In-place exclusive scan: A[gid] = partials[b] + excl_within_block.
//     Safe in-place: every thread reads its element before any write (barriers).
// ---------------------------------------------------------------------------
__global__ __launch_bounds__(1024) void scan_apply_kernel(
    int* __restrict__ A, const int* __restrict__ partials)
{
    __shared__ int sums[1024];
    int t = threadIdx.x;
    int gid = blockIdx.x * 1024 + t;
    int v = (gid < SCAN_N) ? A[gid] : 0;
    sums[t] = v;
    __syncthreads();
    for (int off = 1; off < 1024; off <<= 1) {
        int u = (t >= off) ? sums[t - off] : 0;
        __syncthreads();
        sums[t] += u;
        __syncthreads();
    }
    if (gid < SCAN_N) A[gid] = partials[blockIdx.x] + (sums[t] - v);
}

// ---------------------------------------------------------------------------
// 3) Fill CSR neighbor lists.
// ---------------------------------------------------------------------------
__global__ __launch_bounds__(256) void fill_kernel(
    const int* __restrict__ edge_src, const int* __restrict__ edge_dst,
    const int* __restrict__ A /*row_start*/, int* __restrict__ cursor,
    int* __restrict__ csr)
{
    int e = blockIdx.x * 256 + threadIdx.x;
    if (e >= N_EDGES) return;
    int dst = edge_dst[e];
    int pos = A[dst] + atomicAdd(&cursor[dst], 1);
    csr[pos] = edge_src[e];
}

// ---------------------------------------------------------------------------
// 4) Pack Wcat = [W ; Wr] (256x128) into bf16 MFMA B-fragment order:
//    frag f = (ct*8+ks)*64 + lane holds 8 bf16: B[k=ks*32+(lane>>4)*8+j][n=ct*16+(lane&15)]
// ---------------------------------------------------------------------------
__global__ __launch_bounds__(256) void conv_w_kernel(
    const float* __restrict__ W, const float* __restrict__ Wr,
    unsigned short* __restrict__ Wtb)
{
    int f = blockIdx.x * 256 + threadIdx.x;     // 0..4095
    int l  = f & 63;
    int ks = (f >> 6) & 7;
    int ct = f >> 9;
    int n  = ct * 16 + (l & 15);
    int kb = ks * 32 + (l >> 4) * 8;
    unsigned int w01, w23, w45, w67;
    unsigned short vals[8];
#pragma unroll
    for (int j = 0; j < 8; ++j) {
        int k = kb + j;
        float w = (k < 128) ? W[k * 128 + n] : Wr[(k - 128) * 128 + n];
        vals[j] = f2bf(w);
    }
    w01 = (unsigned int)vals[0] | ((unsigned int)vals[1] << 16);
    w23 = (unsigned int)vals[2] | ((unsigned int)vals[3] << 16);
    w45 = (unsigned int)vals[4] | ((unsigned int)vals[5] << 16);
    w67 = (unsigned int)vals[6] | ((unsigned int)vals[7] << 16);
    uint4 pk; pk.x = w01; pk.y = w23; pk.z = w45; pk.w = w67;
    ((uint4*)Wtb)[f] = pk;
}

// ---------------------------------------------------------------------------
// 5) Gather-mean: half-wave (32 lanes) per node, register accumulate,
//    unroll x2 for MLP; store mean as bf16. Tiny VGPR -> max occupancy.
// ---------------------------------------------------------------------------
__global__ __launch_bounds__(256) void gather_kernel(
    const float* __restrict__ x, const int* __restrict__ A /*row_start*/,
    const int* __restrict__ csr, unsigned short* __restrict__ meanb)
{
    int t = threadIdx.x;
    int node = blockIdx.x * 8 + (t >> 5);
    int l = t & 31;                       // owns dims 4l..4l+3
    int rs = A[node], re = A[node + 1];
    f32x4 acc = {0.f, 0.f, 0.f, 0.f};
    const float* xp = x + (size_t)l * 4;
    int e = rs;
    for (; e + 1 < re; e += 2) {
        int s0 = csr[e], s1 = csr[e + 1];
        f32x4 v0 = *(const f32x4*)(xp + (size_t)s0 * D);
        f32x4 v1 = *(const f32x4*)(xp + (size_t)s1 * D);
        acc += v0;
        acc += v1;
    }
    if (e < re) {
        int s = csr[e];
        acc += *(const f32x4*)(xp + (size_t)s * D);
    }
    float inv = 1.0f / fmaxf((float)(re - rs), 1.0f);
    acc = acc * inv;
    unsigned int p0 = (unsigned int)f2bf(acc[0]) | ((unsigned int)f2bf(acc[1]) << 16);
    unsigned int p1 = (unsigned int)f2bf(acc[2]) | ((unsigned int)f2bf(acc[3]) << 16);
    uint2 pk; pk.x = p0; pk.y = p1;
    *(uint2*)(meanb + (size_t)node * D + l * 4) = pk;
}

// ---------------------------------------------------------------------------
// 6) MFMA GEMM: out[r][c] = sum_k meanb[r][k]*W[k][c] + x[r][k]*Wr[k][c] + bias[c]
//    Block: 256 thr (4 waves), 128 rows; wave = 32 rows (2 row-tiles) x 128 cols.
//    B (both weights) staged once in LDS in fragment-packed order ->
//    stride-1 16B/lane ds_read_b128, conflict-free.
// ---------------------------------------------------------------------------
__global__ __launch_bounds__(256, 2) void gemm_kernel(
    const unsigned short* __restrict__ meanb,
    const float* __restrict__ x,
    const unsigned short* __restrict__ Wtb,
    const float* __restrict__ bias,
    float* __restrict__ out)
{
    __shared__ unsigned short Bs[128 * 256];   // 64 KiB

    const int t = threadIdx.x;
    const int wave = t >> 6;
    const int lane = t & 63;
    const int r0 = blockIdx.x * 128 + wave * 32;       // wave rows r0..r0+31
    const int arow0 = r0 + (lane & 15);
    const int arow1 = arow0 + 16;
    const int ar0 = (arow0 < N_NODES) ? arow0 : (N_NODES - 1);
    const int ar1 = (arow1 < N_NODES) ? arow1 : (N_NODES - 1);
    const int kO = (lane >> 4) * 8;                    // k-offset in 32-step

    // --- A preloads (issue early; latency hides under B staging) ---
    bf16x8 am0[4], am1[4];
    const unsigned short* mr0 = meanb + (size_t)ar0 * D;
    const unsigned short* mr1 = meanb + (size_t)ar1 * D;
#pragma unroll
    for (int ks = 0; ks < 4; ++ks) {
        am0[ks] = *(const bf16x8*)(mr0 + ks * 32 + kO);
        am1[ks] = *(const bf16x8*)(mr1 + ks * 32 + kO);
    }
    const float* xr0 = x + (size_t)ar0 * D;
    const float* xr1 = x + (size_t)ar1 * D;

    // --- stage B (64 KiB linear copy) ---
    {
        const uint4* src = (const uint4*)Wtb;
        uint4* dst = (uint4*)Bs;
#pragma unroll
        for (int i = 0; i < 16; ++i) dst[t + i * 256] = src[t + i * 256];
    }
    __syncthreads();

    // --- acc init from bias ---
    f32x4 acc0[8], acc1[8];
#pragma unroll
    for (int ct = 0; ct < 8; ++ct) {
        float bv = bias[ct * 16 + (lane & 15)];
        f32x4 b4 = {bv, bv, bv, bv};
        acc0[ct] = b4;
        acc1[ct] = b4;
    }

    const bf16x8* __restrict__ Bp = (const bf16x8*)Bs;

    // --- mean half (ks 0..3) ---
#pragma unroll
    for (int ks = 0; ks < 4; ++ks) {
#pragma unroll
        for (int ct = 0; ct < 8; ++ct) {
            bf16x8 bf = Bp[(ct * 8 + ks) * 64 + lane];
            acc0[ct] = __builtin_amdgcn_mfma_f32_16x16x32_bf16(am0[ks], bf, acc0[ct], 0, 0, 0);
            acc1[ct] = __builtin_amdgcn_mfma_f32_16x16x32_bf16(am1[ks], bf, acc1[ct], 0, 0, 0);
        }
    }

    // --- x half (ks 4..7), cvt fp32->bf16 in-register ---
#pragma unroll
    for (int ks = 0; ks < 4; ++ks) {
        f32x4 x00 = *(const f32x4*)(xr0 + ks * 32 + kO);
        f32x4 x01 = *(const f32x4*)(xr0 + ks * 32 + kO + 4);
        f32x4 x10 = *(const f32x4*)(xr1 + ks * 32 + kO);
        f32x4 x11 = *(const f32x4*)(xr1 + ks * 32 + kO + 4);
        bf16x8 a0, a1;
#pragma unroll
        for (int j = 0; j < 4; ++j) {
            a0[j]     = (short)f2bf(x00[j]);
            a0[4 + j] = (short)f2bf(x01[j]);
            a1[j]     = (short)f2bf(x10[j]);
            a1[4 + j] = (short)f2bf(x11[j]);
        }
#pragma unroll
        for (int ct = 0; ct < 8; ++ct) {
            bf16x8 bf = Bp[(ct * 8 + 4 + ks) * 64 + lane];
            acc0[ct] = __builtin_amdgcn_mfma_f32_16x16x32_bf16(a0, bf, acc0[ct], 0, 0, 0);
            acc1[ct] = __builtin_amdgcn_mfma_f32_16x16x32_bf16(a1, bf, acc1[ct], 0, 0, 0);
        }
    }

    // --- store: C/D layout col=lane&15, row=(lane>>4)*4+reg ---
#pragma unroll
    for (int ct = 0; ct < 8; ++ct) {
        int col = ct * 16 + (lane & 15);
#pragma unroll
        for (int r = 0; r < 4; ++r) {
            int row0 = r0 + (lane >> 4) * 4 + r;
            if (row0 < N_NODES) out[(size_t)row0 * D + col] = acc0[ct][r];
            int row1 = row0 + 16;
            if (row1 < N_NODES) out[(size_t)row1 * D + col] = acc1[ct][r];
        }
    }
}

extern "C" void kernel_launch(void* const* d_in, const int* in_sizes, int n_in,
                              void* d_out, int out_size, void* d_ws, size_t ws_size,
                              hipStream_t stream) {
    const float* x           = (const float*)d_in[0];
    const float* weight      = (const float*)d_in[1];
    const float* root_weight = (const float*)d_in[2];
    const float* bias        = (const float*)d_in[3];
    const int* edge_src      = (const int*)d_in[4];
    const int* edge_dst      = (const int*)d_in[5];
    float* out = (float*)d_out;

    // ws layout (bytes):
    //   meanb   [0, 25'600'000)                bf16 [N][128]
    //   Wtb     [25'600'000, +65'536)          bf16 fragment-packed [256][128]
    //   A       (+)  int[100001]  row_start (in-place scan)
    //   cursor  (+)  int[100000]
    //   partials(+)  int[128]
    //   csr     (+)  int[640000]
    char* wsb = (char*)d_ws;
    unsigned short* meanb = (unsigned short*)wsb;
    unsigned short* Wtb   = (unsigned short*)(wsb + 25600000);
    int* A        = (int*)(wsb + 25665536);
    int* cursor   = A + SCAN_N;
    int* partials = cursor + N_NODES;
    int* csr      = partials + 128;

    // zero A + cursor (contiguous)
    hipMemsetAsync(A, 0, (size_t)(SCAN_N + N_NODES) * sizeof(int), stream);

    const int eb = (N_EDGES + 255) / 256;   // 2500
    deg_count_kernel<<<eb, 256, 0, stream>>>(edge_dst, A);
    scan_part_kernel<<<SCAN_B, 1024, 0, stream>>>(A, partials);
    scan_offs_kernel<<<1, 128, 0, stream>>>(partials);
    scan_apply_kernel<<<SCAN_B, 1024, 0, stream>>>(A, partials);
    fill_kernel<<<eb, 256, 0, stream>>>(edge_src, edge_dst, A, cursor, csr);
    conv_w_kernel<<<16, 256, 0, stream>>>(weight, root_weight, Wtb);
    gather_kernel<<<N_NODES / 8, 256, 0, stream>>>(x, A, csr, meanb);

    const int gemm_blocks = (N_NODES + 127) / 128;   // 782
    gemm_kernel<<<gemm_blocks, 256, 0, stream>>>(meanb, x, Wtb, bias, out);
}